// Round 12
// baseline (635.450 us; speedup 1.0000x reference)
//
#include <hip/hip_runtime.h>

#define N_PTS 32768
#define HID   100
#define STEPS 100
#define NPAIR 52   // hidden padded 100 -> 104, stored as 52 (j,j+1) pairs
#define LPP   13   // pairs per lane (4 lanes/point * 13 pairs * 2 j = 104)

// Output layout (concatenated flat, fp32):
#define OFF_Z     0
#define OFF_MUXZ  65536
#define OFF_LSXZ  163840
#define OFF_MUZX  262144
#define OFF_LTZX  327680
#define OFF_MUZ   360448
#define OFF_LTZ   425984

typedef float v2f __attribute__((ext_vector_type(2)));
typedef float v4f __attribute__((ext_vector_type(4)));

#if __has_builtin(__builtin_elementwise_fma)
#define FMA2(a, b, c) __builtin_elementwise_fma((a), (b), (c))
#else
#define FMA2(a, b, c) ((a) * (b) + (c))
#endif
#define LOv(q) __builtin_shufflevector((q), (q), 0, 1)
#define HIv(q) __builtin_shufflevector((q), (q), 2, 3)

__device__ __forceinline__ v2f splat(float x) { v2f r; r.x = x; r.y = x; return r; }

// Butterfly sum across a quad of lanes via DPP quad_perm (xor1=0xB1, xor2=0x4E).
__device__ __forceinline__ float qreduce(float v) {
  v += __int_as_float(__builtin_amdgcn_update_dpp(0, __float_as_int(v), 0xB1, 0xF, 0xF, true));
  v += __int_as_float(__builtin_amdgcn_update_dpp(0, __float_as_int(v), 0x4E, 0xF, 0xF, true));
  return v;
}
// horizontal (even/odd j partials) then quad reduce
__device__ __forceinline__ float hqreduce(v2f v) { return qreduce(v.x + v.y); }

// ---------------- Encoder: x -> h1 -> h2 -> (mu_zx, log_t_zx) ----------------
// Standalone kernel (verified R4: ~33 us). 512 blocks x 256 threads = 4 waves
// covering 64 points; wave w handles h2 chunk {26,26,24,24} at ob {0,26,52,76}.
template<int NP>
__device__ __forceinline__ void enc_chunk(
    int ob, float x0, float x1, float x2,
    const float* __restrict__ We1, const float* __restrict__ be1,
    const float* __restrict__ We2, const float* __restrict__ be2,
    const float* __restrict__ Wmu, const float* __restrict__ Wlt,
    float& m0, float& m1, float& lt)
{
  v2f acc2[NP];
  #pragma unroll
  for (int i = 0; i < NP; ++i) acc2[i] = splat(0.f);

  #pragma unroll 2
  for (int k = 0; k < HID; k += 2) {
    const v2f w0 = *(const v2f*)(We1 + k);
    const v2f w1 = *(const v2f*)(We1 + HID + k);
    const v2f w2 = *(const v2f*)(We1 + 2*HID + k);
    const v2f bb = *(const v2f*)(be1 + k);
    v2f aP = FMA2(splat(x0), w0, FMA2(splat(x1), w1, FMA2(splat(x2), w2, bb)));
    const float e0 = __expf(-aP.x), e1 = __expf(-aP.y);
    const float s0 = 1.f / (1.f + e0), s1 = 1.f / (1.f + e1);
    const v2f hh0 = splat(aP.x * s0);
    const v2f hh1 = splat(aP.y * s1);
    const v2f* r0 = (const v2f*)(We2 + k*HID + ob);        // 8B-aligned (even)
    const v2f* r1 = (const v2f*)(We2 + (k+1)*HID + ob);
    #pragma unroll
    for (int oo = 0; oo < NP; ++oo) {
      v2f tacc = FMA2(hh0, r0[oo], acc2[oo]);   // k then k+1: baseline order
      acc2[oo] = FMA2(hh1, r1[oo], tacc);
    }
  }

  m0 = 0.f; m1 = 0.f; lt = 0.f;
  #pragma unroll
  for (int oo = 0; oo < NP; ++oo) {
    #pragma unroll
    for (int h = 0; h < 2; ++h) {
      const int o = ob + 2*oo + h;
      float a   = (h ? acc2[oo].y : acc2[oo].x) + be2[o];
      float sig = 1.f / (1.f + __expf(-a));
      float h2  = a * sig;
      m0 = fmaf(h2, Wmu[o*2+0], m0);
      m1 = fmaf(h2, Wmu[o*2+1], m1);
      lt = fmaf(h2, Wlt[o],     lt);
    }
  }
}

__global__ __launch_bounds__(256, 2) void enc_kernel(
    const float* __restrict__ x,
    const float* __restrict__ We1, const float* __restrict__ be1,
    const float* __restrict__ We2, const float* __restrict__ be2,
    const float* __restrict__ Wmu, const float* __restrict__ bmu,
    const float* __restrict__ Wlt, const float* __restrict__ blt,
    const float* __restrict__ b_muz, const float* __restrict__ b_ltz,
    float* __restrict__ out)
{
  const int tid = threadIdx.x;
  const int w   = tid >> 6;           // wave 0..3
  const int pb  = tid & 63;           // point within block
  const int p   = blockIdx.x * 64 + pb;

  const float x0 = x[p*3+0], x1 = x[p*3+1], x2 = x[p*3+2];

  float m0, m1, lt;
  if (w < 2) enc_chunk<13>(w * 26,            x0, x1, x2, We1, be1, We2, be2, Wmu, Wlt, m0, m1, lt);
  else       enc_chunk<12>(52 + (w - 2) * 24, x0, x1, x2, We1, be1, We2, be2, Wmu, Wlt, m0, m1, lt);

  __shared__ float red[4][64][3];
  red[w][pb][0] = m0; red[w][pb][1] = m1; red[w][pb][2] = lt;
  __syncthreads();
  if (w == 0) {
    m0 += red[1][pb][0] + red[2][pb][0] + red[3][pb][0] + bmu[0];
    m1 += red[1][pb][1] + red[2][pb][1] + red[3][pb][1] + bmu[1];
    lt += red[1][pb][2] + red[2][pb][2] + red[3][pb][2] + blt[0];
    out[OFF_MUZX + p*2+0] = m0;
    out[OFF_MUZX + p*2+1] = m1;
    out[OFF_LTZX + p]     = lt;
    out[OFF_MUZ  + p*2+0] = b_muz[0];
    out[OFF_MUZ  + p*2+1] = b_muz[1];
    out[OFF_LTZ  + p]     = b_ltz[0];
  }
}

// ------------- SDE: dual-point ILP experiment ----------------
// 4 lanes/point (measured optimum, R4/R10), but each quad now owns TWO points:
// block = 256 thr = 64 quads = 128 points, grid 256 -> 1024 waves = 1/SIMD.
// Zero added per-point work (unlike R10's 8-lane +55%); gains come from:
//  (a) each ds_read_b128 of wrec feeds BOTH points' FMAs (LDS/work halved),
//  (b) two independent dep-chains per wave fill the ~26% stall that TLP left
//      (j-loop activation chains + two independent serial tails),
//  (c) one float4 noise load serves both points.
// Per-point math is a verbatim transcription of the R4/R11 verified sequence.
// __launch_bounds__(256,1): VGPR budget 512 - no R9-style cap spill possible.
// Pair loop stays ROLLED (unroll 2, loop-carried pointer) - R1 LICM hazard.
// All struct members / array indices are compile-time constants (no scratch).
struct Acc {
  v2f Jm00, Jm01, Jm10, Jm11, Jm20, Jm21;
  v2f Js00, Js01, Js10, Js11, Js20, Js21;
  v2f Km00, Km01, Km02, Km10, Km11, Km12, Km20, Km21, Km22;
  v2f Ks00, Ks01, Ks02, Ks10, Ks11, Ks12, Ks20, Ks21, Ks22;
};

__device__ __forceinline__ void acc_zero(Acc& A) {
  const v2f z = splat(0.f);
  A.Jm00=z; A.Jm01=z; A.Jm10=z; A.Jm11=z; A.Jm20=z; A.Jm21=z;
  A.Js00=z; A.Js01=z; A.Js10=z; A.Js11=z; A.Js20=z; A.Js21=z;
  A.Km00=z; A.Km01=z; A.Km02=z; A.Km10=z; A.Km11=z; A.Km12=z;
  A.Km20=z; A.Km21=z; A.Km22=z;
  A.Ks00=z; A.Ks01=z; A.Ks02=z; A.Ks10=z; A.Ks11=z; A.Ks12=z;
  A.Ks20=z; A.Ks21=z; A.Ks22=z;
}

__device__ __forceinline__ void pair_update(
    float z0, float z1,
    v2f W0P, v2f W1P, v2f bP, v2f W11P, v2f W00P, v2f W01P,
    v2f mP0, v2f mP1, v2f mP2, v2f sP0, v2f sP1, v2f sP2,
    Acc& A)
{
  const v2f z0P = splat(z0), z1P = splat(z1);
  v2f aP = FMA2(z0P, W0P, FMA2(z1P, W1P, bP));
  v2f eP;   eP.x   = __expf(-aP.x);               eP.y   = __expf(-aP.y);
  v2f dP = splat(1.f) + eP;
  v2f sigP; sigP.x = __builtin_amdgcn_rcpf(dP.x); sigP.y = __builtin_amdgcn_rcpf(dP.y);
  const v2f ppP  = FMA2(-sigP, sigP, sigP);                 // sig(1-sig)
  const v2f uP   = FMA2(aP, ppP, sigP);                     // swish'
  const v2f w2sP = FMA2(splat(-2.f), sigP, splat(1.f));     // 1-2sig
  const v2f u2P  = FMA2(uP, w2sP, sigP);                    // swish''
  const v2f c0  = uP  * W0P,  c1  = uP  * W1P;
  const v2f q00 = u2P * W00P, q01 = u2P * W01P, q11 = u2P * W11P;

  A.Jm00 = FMA2(c0,  mP0, A.Jm00);  A.Jm01 = FMA2(c1,  mP0, A.Jm01);
  A.Js00 = FMA2(c0,  sP0, A.Js00);  A.Js01 = FMA2(c1,  sP0, A.Js01);
  A.Km00 = FMA2(q00, mP0, A.Km00);  A.Km01 = FMA2(q01, mP0, A.Km01);
  A.Km02 = FMA2(q11, mP0, A.Km02);
  A.Ks00 = FMA2(q00, sP0, A.Ks00);  A.Ks01 = FMA2(q01, sP0, A.Ks01);
  A.Ks02 = FMA2(q11, sP0, A.Ks02);

  A.Jm10 = FMA2(c0,  mP1, A.Jm10);  A.Jm11 = FMA2(c1,  mP1, A.Jm11);
  A.Js10 = FMA2(c0,  sP1, A.Js10);  A.Js11 = FMA2(c1,  sP1, A.Js11);
  A.Km10 = FMA2(q00, mP1, A.Km10);  A.Km11 = FMA2(q01, mP1, A.Km11);
  A.Km12 = FMA2(q11, mP1, A.Km12);
  A.Ks10 = FMA2(q00, sP1, A.Ks10);  A.Ks11 = FMA2(q01, sP1, A.Ks11);
  A.Ks12 = FMA2(q11, sP1, A.Ks12);

  A.Jm20 = FMA2(c0,  mP2, A.Jm20);  A.Jm21 = FMA2(c1,  mP2, A.Jm21);
  A.Js20 = FMA2(c0,  sP2, A.Js20);  A.Js21 = FMA2(c1,  sP2, A.Js21);
  A.Km20 = FMA2(q00, mP2, A.Km20);  A.Km21 = FMA2(q01, mP2, A.Km21);
  A.Km22 = FMA2(q11, mP2, A.Km22);
  A.Ks20 = FMA2(q00, sP2, A.Ks20);  A.Ks21 = FMA2(q01, sP2, A.Ks21);
  A.Ks22 = FMA2(q11, sP2, A.Ks22);
}

// reduce + G/D/inv/drift tail, verbatim R11 math (S/P contraction form).
// Must run on all quad lanes (DPP reads masked lanes as 0).
__device__ __forceinline__ void tail_update(Acc& A, float& z0, float& z1,
                                            float sdt, float nx, float ny)
{
  float JmS[3][2] = {{hqreduce(A.Jm00), hqreduce(A.Jm01)},
                     {hqreduce(A.Jm10), hqreduce(A.Jm11)},
                     {hqreduce(A.Jm20), hqreduce(A.Jm21)}};
  float JsS[3][2] = {{hqreduce(A.Js00), hqreduce(A.Js01)},
                     {hqreduce(A.Js10), hqreduce(A.Js11)},
                     {hqreduce(A.Js20), hqreduce(A.Js21)}};
  float KmS[3][3] = {{hqreduce(A.Km00), hqreduce(A.Km01), hqreduce(A.Km02)},
                     {hqreduce(A.Km10), hqreduce(A.Km11), hqreduce(A.Km12)},
                     {hqreduce(A.Km20), hqreduce(A.Km21), hqreduce(A.Km22)}};
  float KsS[3][3] = {{hqreduce(A.Ks00), hqreduce(A.Ks01), hqreduce(A.Ks02)},
                     {hqreduce(A.Ks10), hqreduce(A.Ks11), hqreduce(A.Ks12)},
                     {hqreduce(A.Ks20), hqreduce(A.Ks21), hqreduce(A.Ks22)}};

  // G = J^T J (2x2 sym)
  float G00=0.f, G01=0.f, G11=0.f;
  #pragma unroll
  for (int o = 0; o < 3; ++o) {
    G00 += JmS[o][0]*JmS[o][0] + JsS[o][0]*JsS[o][0];
    G01 += JmS[o][0]*JmS[o][1] + JsS[o][0]*JsS[o][1];
    G11 += JmS[o][1]*JmS[o][1] + JsS[o][1]*JsS[o][1];
  }
  // D[c][l] = dG[km]/dz_l (sym in k,m)
  float D00=0.f, D01=0.f, D10=0.f, D11=0.f, D20=0.f, D21=0.f;
  #pragma unroll
  for (int o = 0; o < 3; ++o) {
    D00 += 2.f*(KmS[o][0]*JmS[o][0] + KsS[o][0]*JsS[o][0]);
    D01 += 2.f*(KmS[o][1]*JmS[o][0] + KsS[o][1]*JsS[o][0]);
    D10 += KmS[o][0]*JmS[o][1] + JmS[o][0]*KmS[o][1] + KsS[o][0]*JsS[o][1] + JsS[o][0]*KsS[o][1];
    D11 += KmS[o][1]*JmS[o][1] + JmS[o][0]*KmS[o][2] + KsS[o][1]*JsS[o][1] + JsS[o][0]*KsS[o][2];
    D20 += 2.f*(KmS[o][1]*JmS[o][1] + KsS[o][1]*JsS[o][1]);
    D21 += 2.f*(KmS[o][2]*JmS[o][1] + KsS[o][2]*JsS[o][1]);
  }
  const float det = fmaf(G00, G11, -G01*G01);
  const float id  = __builtin_amdgcn_rcpf(det);
  const float i00 = G11*id, i01 = -G01*id, i11 = G00*id;
  // drift via S/P contraction (symbolically identical to the T/Chris form)
  const float S0 = fmaf(i00, D00, fmaf(i01, D01 + D10, i11 * D11));
  const float S1 = fmaf(i00, D10, fmaf(i01, D11 + D20, i11 * D21));
  const float i01d = i01 + i01;
  const float P0 = fmaf(i00, D00, fmaf(i01d, D10, i11 * D20));
  const float P1 = fmaf(i00, D01, fmaf(i01d, D11, i11 * D21));
  const float R0 = fmaf(0.5f, S0, -0.25f * P0);
  const float R1 = fmaf(0.5f, S1, -0.25f * P1);
  const float dr0 = fmaf(i00, R0, i01 * R1);
  const float dr1 = fmaf(i01, R0, i11 * R1);

  const float dw0 = sdt*nx, dw1 = sdt*ny;
  z0 += dr0 + i00*dw0 + i01*dw1;   // + ginv @ dW
  z1 += dr1 + i01*dw0 + i11*dw1;
}

__global__ __launch_bounds__(256, 1) void sde_kernel(
    const float* __restrict__ Wd1,  const float* __restrict__ bd1,
    const float* __restrict__ Wdmu, const float* __restrict__ bdmu,
    const float* __restrict__ Wds,  const float* __restrict__ bds,
    const float* __restrict__ noise,
    float* __restrict__ out)
{
  __shared__ __align__(16) float wrec[NPAIR * 24];
  const int tid = threadIdx.x;
  for (int idx = tid; idx < NPAIR * 24; idx += 256) {
    const int pr = idx / 24, f = idx - pr * 24;
    const int j  = pr * 2 + (f & 1);
    const int g  = f >> 1;      // 0:W0 1:W1 2:b 3:W11 4:W00 5:W01 6..11:m/s
    float v = 0.f;
    if (j < HID) {
      const float w0 = Wd1[j], w1 = Wd1[HID + j];
      switch (g) {
        case 0:  v = w0; break;
        case 1:  v = w1; break;
        case 2:  v = bd1[j]; break;
        case 3:  v = w1 * w1; break;
        case 4:  v = w0 * w0; break;
        case 5:  v = w0 * w1; break;
        case 6:  v = Wdmu[j*3+0]; break;
        case 7:  v = Wds [j*3+0]; break;
        case 8:  v = Wdmu[j*3+1]; break;
        case 9:  v = Wds [j*3+1]; break;
        case 10: v = Wdmu[j*3+2]; break;
        default: v = Wds [j*3+2]; break;
      }
    }
    wrec[idx] = v;
  }
  __syncthreads();

  const int l     = tid & 3;                    // lane within quad
  const int q     = tid >> 2;                   // quad id (0..63)
  const int pA    = blockIdx.x * 128 + q * 2;   // first point of the quad
  const int pB    = pA + 1;                     // second point
  const int pbase = l * LPP;                    // lane's first pair
  const v4f* __restrict__ Rq = (const v4f*)wrec;   // 6 v4f per pair

  float zA0 = out[OFF_MUZX + pA*2+0], zA1 = out[OFF_MUZX + pA*2+1];
  float zB0 = out[OFF_MUZX + pB*2+0], zB1 = out[OFF_MUZX + pB*2+1];
  const float sdtA = __expf(out[OFF_LTZX + pA]) * 0.1f;  // sqrt(dt)
  const float sdtB = __expf(out[OFF_LTZX + pB]) * 0.1f;

  const float4* __restrict__ noise4 = (const float4*)noise;  // 2 pts per load

  for (int step = 0; step < STEPS; ++step) {
    // one 16B load serves both points (pA even -> aligned)
    const float4 nzAB = noise4[((size_t)step * N_PTS + pA) >> 1];

    Acc accA, accB;
    acc_zero(accA); acc_zero(accB);

    // ROLLED loop (unroll 2) with loop-carried pointer: shared weight loads
    // feed both points' chains (LICM-spill hazard documented above).
    const v4f* R = Rq + pbase * 6;
    #pragma unroll 2
    for (int t = 0; t < LPP; ++t, R += 6) {
      const v4f A  = R[0];   // {W0j0,W0j1, W1j0,W1j1}
      const v4f B  = R[1];   // {bj0,bj1, W11j0,W11j1}
      const v4f Cq = R[2];   // {W00j0,W00j1, W01j0,W01j1}
      const v4f M0 = R[3], M1 = R[4], M2 = R[5];
      const v2f W0P  = LOv(A),  W1P  = HIv(A);
      const v2f bP   = LOv(B),  W11P = HIv(B);
      const v2f W00P = LOv(Cq), W01P = HIv(Cq);
      const v2f mP0 = LOv(M0), mP1 = LOv(M1), mP2 = LOv(M2);
      const v2f sP0 = HIv(M0), sP1 = HIv(M1), sP2 = HIv(M2);

      pair_update(zA0, zA1, W0P, W1P, bP, W11P, W00P, W01P,
                  mP0, mP1, mP2, sP0, sP1, sP2, accA);
      pair_update(zB0, zB1, W0P, W1P, bP, W11P, W00P, W01P,
                  mP0, mP1, mP2, sP0, sP1, sP2, accB);
    }

    // two independent serial tails — compiler interleaves the dep chains
    tail_update(accA, zA0, zA1, sdtA, nzAB.x, nzAB.y);
    tail_update(accB, zB0, zB1, sdtB, nzAB.z, nzAB.w);
  }

  // ---- final decode on both z's (shared weight loads again) ----
  v2f MSmA[3], MSsA[3], MSmB[3], MSsB[3];
  #pragma unroll
  for (int o = 0; o < 3; ++o) {
    MSmA[o] = splat(0.f); MSsA[o] = splat(0.f);
    MSmB[o] = splat(0.f); MSsB[o] = splat(0.f);
  }
  const v2f zA0P = splat(zA0), zA1P = splat(zA1);
  const v2f zB0P = splat(zB0), zB1P = splat(zB1);
  {
    const v4f* R = Rq + pbase * 6;
    #pragma unroll 2
    for (int t = 0; t < LPP; ++t, R += 6) {
      const v4f A  = R[0];
      const v4f B  = R[1];
      const v4f M0 = R[3], M1 = R[4], M2 = R[5];
      const v2f W0P = LOv(A), W1P = HIv(A), bP = LOv(B);
      const v2f mP0 = LOv(M0), mP1 = LOv(M1), mP2 = LOv(M2);
      const v2f sP0 = HIv(M0), sP1 = HIv(M1), sP2 = HIv(M2);

      v2f aA = FMA2(zA0P, W0P, FMA2(zA1P, W1P, bP));
      v2f eA;   eA.x   = __expf(-aA.x);               eA.y   = __expf(-aA.y);
      v2f dA = splat(1.f) + eA;
      v2f sgA; sgA.x = __builtin_amdgcn_rcpf(dA.x);   sgA.y = __builtin_amdgcn_rcpf(dA.y);
      const v2f hA = aA * sgA;

      v2f aB = FMA2(zB0P, W0P, FMA2(zB1P, W1P, bP));
      v2f eB;   eB.x   = __expf(-aB.x);               eB.y   = __expf(-aB.y);
      v2f dB = splat(1.f) + eB;
      v2f sgB; sgB.x = __builtin_amdgcn_rcpf(dB.x);   sgB.y = __builtin_amdgcn_rcpf(dB.y);
      const v2f hB = aB * sgB;

      MSmA[0] = FMA2(hA, mP0, MSmA[0]);  MSsA[0] = FMA2(hA, sP0, MSsA[0]);
      MSmA[1] = FMA2(hA, mP1, MSmA[1]);  MSsA[1] = FMA2(hA, sP1, MSsA[1]);
      MSmA[2] = FMA2(hA, mP2, MSmA[2]);  MSsA[2] = FMA2(hA, sP2, MSsA[2]);
      MSmB[0] = FMA2(hB, mP0, MSmB[0]);  MSsB[0] = FMA2(hB, sP0, MSsB[0]);
      MSmB[1] = FMA2(hB, mP1, MSmB[1]);  MSsB[1] = FMA2(hB, sP1, MSsB[1]);
      MSmB[2] = FMA2(hB, mP2, MSmB[2]);  MSsB[2] = FMA2(hB, sP2, MSsB[2]);
    }
  }
  // reductions must run on all quad lanes (DPP reads masked lanes as 0)
  float muA[3], lsA[3], muB[3], lsB[3];
  #pragma unroll
  for (int o = 0; o < 3; ++o) {
    muA[o] = hqreduce(MSmA[o]); lsA[o] = hqreduce(MSsA[o]);
    muB[o] = hqreduce(MSmB[o]); lsB[o] = hqreduce(MSsB[o]);
  }

  if (l == 0) {
    out[OFF_Z + pA*2+0] = zA0;  out[OFF_Z + pA*2+1] = zA1;
    out[OFF_Z + pB*2+0] = zB0;  out[OFF_Z + pB*2+1] = zB1;
    #pragma unroll
    for (int o = 0; o < 3; ++o) {
      out[OFF_MUXZ + pA*3 + o] = muA[o] + bdmu[o];
      out[OFF_LSXZ + pA*3 + o] = lsA[o] + bds[o];
      out[OFF_MUXZ + pB*3 + o] = muB[o] + bdmu[o];
      out[OFF_LSXZ + pB*3 + o] = lsB[o] + bds[o];
    }
  }
}

extern "C" void kernel_launch(void* const* d_in, const int* in_sizes, int n_in,
                              void* d_out, int out_size, void* d_ws, size_t ws_size,
                              hipStream_t stream) {
  (void)in_sizes; (void)n_in; (void)d_ws; (void)ws_size; (void)out_size;
  const float* x    = (const float*)d_in[0];
  const float* We1  = (const float*)d_in[1];
  const float* be1  = (const float*)d_in[2];
  const float* We2  = (const float*)d_in[3];
  const float* be2  = (const float*)d_in[4];
  const float* Wmu  = (const float*)d_in[5];
  const float* bmu  = (const float*)d_in[6];
  const float* Wlt  = (const float*)d_in[7];
  const float* blt  = (const float*)d_in[8];
  const float* Wd1  = (const float*)d_in[9];
  const float* bd1  = (const float*)d_in[10];
  const float* Wdmu = (const float*)d_in[11];
  const float* bdmu = (const float*)d_in[12];
  const float* Wds  = (const float*)d_in[13];
  const float* bds  = (const float*)d_in[14];
  const float* bmz  = (const float*)d_in[15];
  const float* blz  = (const float*)d_in[16];
  const float* noise= (const float*)d_in[17];
  float* out = (float*)d_out;

  enc_kernel<<<512, 256, 0, stream>>>(x, We1, be1, We2, be2, Wmu, bmu, Wlt, blt,
                                      bmz, blz, out);
  sde_kernel<<<256, 256, 0, stream>>>(Wd1, bd1, Wdmu, bdmu, Wds, bds, noise, out);
}

// Round 13
// 574.017 us; speedup vs baseline: 1.1070x; 1.1070x over previous
//
#include <hip/hip_runtime.h>

#define N_PTS 32768
#define HID   100
#define STEPS 100
#define NPAIR 52   // hidden padded 100 -> 104, stored as 52 (j,j+1) pairs
#define LPP   13   // pairs per lane (4 lanes/point * 13 pairs * 2 j = 104)

// Output layout (concatenated flat, fp32):
#define OFF_Z     0
#define OFF_MUXZ  65536
#define OFF_LSXZ  163840
#define OFF_MUZX  262144
#define OFF_LTZX  327680
#define OFF_MUZ   360448
#define OFF_LTZ   425984

typedef float v2f __attribute__((ext_vector_type(2)));
typedef float v4f __attribute__((ext_vector_type(4)));

#if __has_builtin(__builtin_elementwise_fma)
#define FMA2(a, b, c) __builtin_elementwise_fma((a), (b), (c))
#else
#define FMA2(a, b, c) ((a) * (b) + (c))
#endif
#define LOv(q) __builtin_shufflevector((q), (q), 0, 1)
#define HIv(q) __builtin_shufflevector((q), (q), 2, 3)

__device__ __forceinline__ v2f splat(float x) { v2f r; r.x = x; r.y = x; return r; }

// Butterfly sum across a quad of lanes via DPP quad_perm (xor1=0xB1, xor2=0x4E).
__device__ __forceinline__ float qreduce(float v) {
  v += __int_as_float(__builtin_amdgcn_update_dpp(0, __float_as_int(v), 0xB1, 0xF, 0xF, true));
  v += __int_as_float(__builtin_amdgcn_update_dpp(0, __float_as_int(v), 0x4E, 0xF, 0xF, true));
  return v;
}
// horizontal (even/odd j partials) then quad reduce
__device__ __forceinline__ float hqreduce(v2f v) { return qreduce(v.x + v.y); }

// ---------------- Encoder chunk: x -> h1 -> h2 partial -> (m0,m1,lt) ----------
// Wave w handles h2 output chunk {26,26,24,24} at ob {0,26,52,76} (even offsets
// keep v2f loads aligned).
template<int NP>
__device__ __forceinline__ void enc_chunk(
    int ob, float x0, float x1, float x2,
    const float* __restrict__ We1, const float* __restrict__ be1,
    const float* __restrict__ We2, const float* __restrict__ be2,
    const float* __restrict__ Wmu, const float* __restrict__ Wlt,
    float& m0, float& m1, float& lt)
{
  v2f acc2[NP];
  #pragma unroll
  for (int i = 0; i < NP; ++i) acc2[i] = splat(0.f);

  #pragma unroll 2
  for (int k = 0; k < HID; k += 2) {
    const v2f w0 = *(const v2f*)(We1 + k);
    const v2f w1 = *(const v2f*)(We1 + HID + k);
    const v2f w2 = *(const v2f*)(We1 + 2*HID + k);
    const v2f bb = *(const v2f*)(be1 + k);
    // identical fma nesting to baseline, packed over the k-pair
    v2f aP = FMA2(splat(x0), w0, FMA2(splat(x1), w1, FMA2(splat(x2), w2, bb)));
    const float e0 = __expf(-aP.x), e1 = __expf(-aP.y);
    const float s0 = 1.f / (1.f + e0), s1 = 1.f / (1.f + e1);
    const v2f hh0 = splat(aP.x * s0);
    const v2f hh1 = splat(aP.y * s1);
    const v2f* r0 = (const v2f*)(We2 + k*HID + ob);        // 8B-aligned (even)
    const v2f* r1 = (const v2f*)(We2 + (k+1)*HID + ob);
    #pragma unroll
    for (int oo = 0; oo < NP; ++oo) {
      v2f tacc = FMA2(hh0, r0[oo], acc2[oo]);   // k then k+1: baseline order
      acc2[oo] = FMA2(hh1, r1[oo], tacc);
    }
  }

  m0 = 0.f; m1 = 0.f; lt = 0.f;
  #pragma unroll
  for (int oo = 0; oo < NP; ++oo) {
    #pragma unroll
    for (int h = 0; h < 2; ++h) {
      const int o = ob + 2*oo + h;
      float a   = (h ? acc2[oo].y : acc2[oo].x) + be2[o];
      float sig = 1.f / (1.f + __expf(-a));
      float h2  = a * sig;
      m0 = fmaf(h2, Wmu[o*2+0], m0);
      m1 = fmaf(h2, Wmu[o*2+1], m1);
      lt = fmaf(h2, Wlt[o],     lt);
    }
  }
}

// ---------------- Fused kernel: encoder -> SDE -> final decode ----------------
// Block = 256 threads = 64 points. Phase 1 (encoder): 4 waves each compute a
// partial h2 chunk for all 64 points; quad-sum via LDS; mu/lt pass to phase 2
// through LDS (no global round-trip, no second launch).
// Phase 2 (SDE): 4 lanes per point; each lane owns 13 j-PAIRS (hidden padded
// to 104 with zero records — exact-zero contributions through swish derivs).
// The point-decomposition space is fully measured; busy work is invariant at
// ~390 us*SIMD across all three, so stall coverage decides:
//   4 lanes/pt, 2 waves/SIMD (this kernel): sde 522 us, 74% busy  <- optimum
//   8 lanes/pt, 4 waves/SIMD (R10): 717 us (+55% work: dup reduce/tail)
//   4 lanes/pt dual-point, 1 wave/SIMD (R12): 586 us (ILP < TLP for stalls)
// LDS record per pair = 24 floats (96 B, 6 x ds_read_b128), j-major pairs so
// v_pk ops consume loaded register pairs directly:
//   {W0j0,W0j1, W1j0,W1j1 | bj0,bj1, W11j0,W11j1 | W00j0,W00j1, W01j0,W01j1 |
//    m0j0,m0j1, s0j0,s0j1 | m1j0,m1j1, s1j0,s1j1 | m2j0,m2j1, s2j0,s2j1}
// CRITICAL: the pair loop must stay ROLLED (partial unroll only). Fully
// unrolling it makes all 78 ds_reads loop-invariant in the step loop; LICM
// hoists ~312 dwords of LDS into registers, regalloc spills to scratch, and
// the step loop re-reads scratch instead of LDS (round-1 post-mortem:
// FETCH_SIZE 13 MB -> 4.13 GB, VALUBusy 78 -> 25%). Do NOT precompute weight
// products into wider records either: 17 reads/pair saturates the LDS pipe
// (round 6: +15%). 6 reads/pair is the balanced point.
__global__ __launch_bounds__(256, 2) void vaebm_kernel(
    const float* __restrict__ x,
    const float* __restrict__ We1, const float* __restrict__ be1,
    const float* __restrict__ We2, const float* __restrict__ be2,
    const float* __restrict__ Wmu, const float* __restrict__ bmu,
    const float* __restrict__ Wlt, const float* __restrict__ blt,
    const float* __restrict__ Wd1,  const float* __restrict__ bd1,
    const float* __restrict__ Wdmu, const float* __restrict__ bdmu,
    const float* __restrict__ Wds,  const float* __restrict__ bds,
    const float* __restrict__ b_muz, const float* __restrict__ b_ltz,
    const float* __restrict__ noise,
    float* __restrict__ out)
{
  __shared__ __align__(16) float wrec[NPAIR * 24];
  __shared__ float red[4][64][3];
  __shared__ float zlds[64][3];

  const int tid = threadIdx.x;

  // ---- SDE weight-record fill (independent of encoder; loads overlap it) ----
  for (int idx = tid; idx < NPAIR * 24; idx += 256) {
    const int pr = idx / 24, f = idx - pr * 24;
    const int j  = pr * 2 + (f & 1);
    const int g  = f >> 1;      // 0:W0 1:W1 2:b 3:W11 4:W00 5:W01 6..11:m/s
    float v = 0.f;
    if (j < HID) {
      const float w0 = Wd1[j], w1 = Wd1[HID + j];
      switch (g) {
        case 0:  v = w0; break;
        case 1:  v = w1; break;
        case 2:  v = bd1[j]; break;
        case 3:  v = w1 * w1; break;
        case 4:  v = w0 * w0; break;
        case 5:  v = w0 * w1; break;
        case 6:  v = Wdmu[j*3+0]; break;
        case 7:  v = Wds [j*3+0]; break;
        case 8:  v = Wdmu[j*3+1]; break;
        case 9:  v = Wds [j*3+1]; break;
        case 10: v = Wdmu[j*3+2]; break;
        default: v = Wds [j*3+2]; break;
      }
    }
    wrec[idx] = v;
  }

  // ---- Phase 1: encoder ----
  const int w  = tid >> 6;            // wave 0..3
  const int pb = tid & 63;            // point within block
  const int p  = blockIdx.x * 64 + pb;

  const float x0 = x[p*3+0], x1 = x[p*3+1], x2 = x[p*3+2];

  float m0, m1, lt;
  if (w < 2) enc_chunk<13>(w * 26,            x0, x1, x2, We1, be1, We2, be2, Wmu, Wlt, m0, m1, lt);
  else       enc_chunk<12>(52 + (w - 2) * 24, x0, x1, x2, We1, be1, We2, be2, Wmu, Wlt, m0, m1, lt);

  red[w][pb][0] = m0; red[w][pb][1] = m1; red[w][pb][2] = lt;
  __syncthreads();
  if (w == 0) {
    m0 += red[1][pb][0] + red[2][pb][0] + red[3][pb][0] + bmu[0];
    m1 += red[1][pb][1] + red[2][pb][1] + red[3][pb][1] + bmu[1];
    lt += red[1][pb][2] + red[2][pb][2] + red[3][pb][2] + blt[0];
    out[OFF_MUZX + p*2+0] = m0;
    out[OFF_MUZX + p*2+1] = m1;
    out[OFF_LTZX + p]     = lt;
    out[OFF_MUZ  + p*2+0] = b_muz[0];
    out[OFF_MUZ  + p*2+1] = b_muz[1];
    out[OFF_LTZ  + p]     = b_ltz[0];
    zlds[pb][0] = m0; zlds[pb][1] = m1; zlds[pb][2] = lt;
  }
  __syncthreads();

  // ---- Phase 2: SDE (100 Euler-Maruyama steps on the pullback metric) ----
  const int l     = tid & 3;                    // lane within quad
  const int pt    = tid >> 2;                   // point within block
  const int pg    = blockIdx.x * 64 + pt;       // global point
  const int pbase = l * LPP;                    // lane's first pair
  const v4f* __restrict__ Rq = (const v4f*)wrec;   // 6 v4f per pair

  float z0 = zlds[pt][0];
  float z1 = zlds[pt][1];
  const float sdt = __expf(zlds[pt][2]) * 0.1f;  // sqrt(dt) = exp(lt)/sqrt(100)

  const float2* __restrict__ noise2 = (const float2*)noise;

  for (int step = 0; step < STEPS; ++step) {
    // issue the noise load early; its latency hides under the j-loop
    const float2 nz = noise2[(size_t)step * N_PTS + pg];

    v2f Jm[3][2], Js[3][2], Km[3][3], Ks[3][3];
    #pragma unroll
    for (int o = 0; o < 3; ++o) {
      Jm[o][0]=splat(0.f); Jm[o][1]=splat(0.f);
      Js[o][0]=splat(0.f); Js[o][1]=splat(0.f);
      Km[o][0]=splat(0.f); Km[o][1]=splat(0.f); Km[o][2]=splat(0.f);
      Ks[o][0]=splat(0.f); Ks[o][1]=splat(0.f); Ks[o][2]=splat(0.f);
    }
    const v2f z0P = splat(z0), z1P = splat(z1);

    // ROLLED loop (partial unroll) with loop-carried pointer: keeps the
    // ds_reads inside the step loop body (see comment above the kernel).
    const v4f* R = Rq + pbase * 6;
    #pragma unroll 4
    for (int t = 0; t < LPP; ++t, R += 6) {
      const v4f A  = R[0];   // {W0j0,W0j1, W1j0,W1j1}
      const v4f B  = R[1];   // {bj0,bj1, W11j0,W11j1}
      const v4f Cq = R[2];   // {W00j0,W00j1, W01j0,W01j1}
      const v4f M0 = R[3], M1 = R[4], M2 = R[5];
      const v2f W0P  = LOv(A),  W1P  = HIv(A);
      const v2f bP   = LOv(B),  W11P = HIv(B);
      const v2f W00P = LOv(Cq), W01P = HIv(Cq);

      v2f aP = FMA2(z0P, W0P, FMA2(z1P, W1P, bP));
      v2f eP;   eP.x   = __expf(-aP.x);               eP.y   = __expf(-aP.y);
      v2f dP = splat(1.f) + eP;
      v2f sigP; sigP.x = __builtin_amdgcn_rcpf(dP.x); sigP.y = __builtin_amdgcn_rcpf(dP.y);
      const v2f ppP  = FMA2(-sigP, sigP, sigP);                 // sig(1-sig)
      const v2f uP   = FMA2(aP, ppP, sigP);                     // swish'
      const v2f w2sP = FMA2(splat(-2.f), sigP, splat(1.f));     // 1-2sig
      const v2f u2P  = FMA2(uP, w2sP, sigP);  // swish'' = u(1-2s)+s (exact:
                                              // = 2pp + a*pp*(1-2s))
      const v2f c0  = uP  * W0P,  c1  = uP  * W1P;
      const v2f q00 = u2P * W00P, q01 = u2P * W01P, q11 = u2P * W11P;

      const v2f mP0 = LOv(M0), mP1 = LOv(M1), mP2 = LOv(M2);
      const v2f sP0 = HIv(M0), sP1 = HIv(M1), sP2 = HIv(M2);

      Jm[0][0] = FMA2(c0,  mP0, Jm[0][0]);  Jm[0][1] = FMA2(c1,  mP0, Jm[0][1]);
      Js[0][0] = FMA2(c0,  sP0, Js[0][0]);  Js[0][1] = FMA2(c1,  sP0, Js[0][1]);
      Km[0][0] = FMA2(q00, mP0, Km[0][0]);  Km[0][1] = FMA2(q01, mP0, Km[0][1]);
      Km[0][2] = FMA2(q11, mP0, Km[0][2]);
      Ks[0][0] = FMA2(q00, sP0, Ks[0][0]);  Ks[0][1] = FMA2(q01, sP0, Ks[0][1]);
      Ks[0][2] = FMA2(q11, sP0, Ks[0][2]);

      Jm[1][0] = FMA2(c0,  mP1, Jm[1][0]);  Jm[1][1] = FMA2(c1,  mP1, Jm[1][1]);
      Js[1][0] = FMA2(c0,  sP1, Js[1][0]);  Js[1][1] = FMA2(c1,  sP1, Js[1][1]);
      Km[1][0] = FMA2(q00, mP1, Km[1][0]);  Km[1][1] = FMA2(q01, mP1, Km[1][1]);
      Km[1][2] = FMA2(q11, mP1, Km[1][2]);
      Ks[1][0] = FMA2(q00, sP1, Ks[1][0]);  Ks[1][1] = FMA2(q01, sP1, Ks[1][1]);
      Ks[1][2] = FMA2(q11, sP1, Ks[1][2]);

      Jm[2][0] = FMA2(c0,  mP2, Jm[2][0]);  Jm[2][1] = FMA2(c1,  mP2, Jm[2][1]);
      Js[2][0] = FMA2(c0,  sP2, Js[2][0]);  Js[2][1] = FMA2(c1,  sP2, Js[2][1]);
      Km[2][0] = FMA2(q00, mP2, Km[2][0]);  Km[2][1] = FMA2(q01, mP2, Km[2][1]);
      Km[2][2] = FMA2(q11, mP2, Km[2][2]);
      Ks[2][0] = FMA2(q00, sP2, Ks[2][0]);  Ks[2][1] = FMA2(q01, sP2, Ks[2][1]);
      Ks[2][2] = FMA2(q11, sP2, Ks[2][2]);
    }

    // fold even/odd-j partials, then complete the j-sums across the quad
    float JmS[3][2], JsS[3][2], KmS[3][3], KsS[3][3];
    #pragma unroll
    for (int o = 0; o < 3; ++o) {
      JmS[o][0]=hqreduce(Jm[o][0]); JmS[o][1]=hqreduce(Jm[o][1]);
      JsS[o][0]=hqreduce(Js[o][0]); JsS[o][1]=hqreduce(Js[o][1]);
      KmS[o][0]=hqreduce(Km[o][0]); KmS[o][1]=hqreduce(Km[o][1]); KmS[o][2]=hqreduce(Km[o][2]);
      KsS[o][0]=hqreduce(Ks[o][0]); KsS[o][1]=hqreduce(Ks[o][1]); KsS[o][2]=hqreduce(Ks[o][2]);
    }

    // G = J^T J (2x2 sym)
    float G00=0.f, G01=0.f, G11=0.f;
    #pragma unroll
    for (int o = 0; o < 3; ++o) {
      G00 += JmS[o][0]*JmS[o][0] + JsS[o][0]*JsS[o][0];
      G01 += JmS[o][0]*JmS[o][1] + JsS[o][0]*JsS[o][1];
      G11 += JmS[o][1]*JmS[o][1] + JsS[o][1]*JsS[o][1];
    }
    // D[c][l] = dG[km]/dz_l (sym in k,m)
    float D00=0.f, D01=0.f, D10=0.f, D11=0.f, D20=0.f, D21=0.f;
    #pragma unroll
    for (int o = 0; o < 3; ++o) {
      D00 += 2.f*(KmS[o][0]*JmS[o][0] + KsS[o][0]*JsS[o][0]);
      D01 += 2.f*(KmS[o][1]*JmS[o][0] + KsS[o][1]*JsS[o][0]);
      D10 += KmS[o][0]*JmS[o][1] + JmS[o][0]*KmS[o][1] + KsS[o][0]*JsS[o][1] + JsS[o][0]*KsS[o][1];
      D11 += KmS[o][1]*JmS[o][1] + JmS[o][0]*KmS[o][2] + KsS[o][1]*JsS[o][1] + JsS[o][0]*KsS[o][2];
      D20 += 2.f*(KmS[o][1]*JmS[o][1] + KsS[o][1]*JsS[o][1]);
      D21 += 2.f*(KmS[o][2]*JmS[o][1] + KsS[o][2]*JsS[o][1]);
    }
    const float det = fmaf(G00, G11, -G01*G01);
    const float id  = __builtin_amdgcn_rcpf(det);
    const float i00 = G11*id, i01 = -G01*id, i11 = G00*id;
    // drift via S/P contraction (symbolically identical to the T/Chris form):
    //   S_m = ginv_jk Dg[j,m,k], P_m = ginv_jk Dg[j,k,m]
    //   dr_i = 0.25 * ginv_im * (2 S_m - P_m)
    const float S0 = fmaf(i00, D00, fmaf(i01, D01 + D10, i11 * D11));
    const float S1 = fmaf(i00, D10, fmaf(i01, D11 + D20, i11 * D21));
    const float i01d = i01 + i01;
    const float P0 = fmaf(i00, D00, fmaf(i01d, D10, i11 * D20));
    const float P1 = fmaf(i00, D01, fmaf(i01d, D11, i11 * D21));
    const float R0 = fmaf(0.5f, S0, -0.25f * P0);
    const float R1 = fmaf(0.5f, S1, -0.25f * P1);
    const float dr0 = fmaf(i00, R0, i01 * R1);
    const float dr1 = fmaf(i01, R0, i11 * R1);

    const float dw0 = sdt*nz.x, dw1 = sdt*nz.y;
    z0 += dr0 + i00*dw0 + i01*dw1;   // + ginv @ dW
    z1 += dr1 + i01*dw0 + i11*dw1;
  }

  // ---- final decode on z ----
  v2f MSm[3], MSs[3];
  #pragma unroll
  for (int o = 0; o < 3; ++o) { MSm[o] = splat(0.f); MSs[o] = splat(0.f); }
  const v2f zf0 = splat(z0), zf1 = splat(z1);
  {
    const v4f* R = Rq + pbase * 6;
    #pragma unroll 2
    for (int t = 0; t < LPP; ++t, R += 6) {
      const v4f A  = R[0];
      const v4f B  = R[1];
      const v4f M0 = R[3], M1 = R[4], M2 = R[5];
      v2f aP = FMA2(zf0, LOv(A), FMA2(zf1, HIv(A), LOv(B)));
      v2f eP;   eP.x   = __expf(-aP.x);               eP.y   = __expf(-aP.y);
      v2f dP = splat(1.f) + eP;
      v2f sigP; sigP.x = __builtin_amdgcn_rcpf(dP.x); sigP.y = __builtin_amdgcn_rcpf(dP.y);
      const v2f hP = aP * sigP;
      MSm[0] = FMA2(hP, LOv(M0), MSm[0]);  MSs[0] = FMA2(hP, HIv(M0), MSs[0]);
      MSm[1] = FMA2(hP, LOv(M1), MSm[1]);  MSs[1] = FMA2(hP, HIv(M1), MSs[1]);
      MSm[2] = FMA2(hP, LOv(M2), MSm[2]);  MSs[2] = FMA2(hP, HIv(M2), MSs[2]);
    }
  }
  // reductions must run on all quad lanes (DPP reads masked lanes as 0)
  float mu[3], ls[3];
  #pragma unroll
  for (int o = 0; o < 3; ++o) { mu[o] = hqreduce(MSm[o]); ls[o] = hqreduce(MSs[o]); }

  if (l == 0) {
    out[OFF_Z + pg*2+0] = z0;
    out[OFF_Z + pg*2+1] = z1;
    #pragma unroll
    for (int o = 0; o < 3; ++o) {
      out[OFF_MUXZ + pg*3 + o] = mu[o] + bdmu[o];
      out[OFF_LSXZ + pg*3 + o] = ls[o] + bds[o];
    }
  }
}

extern "C" void kernel_launch(void* const* d_in, const int* in_sizes, int n_in,
                              void* d_out, int out_size, void* d_ws, size_t ws_size,
                              hipStream_t stream) {
  (void)in_sizes; (void)n_in; (void)d_ws; (void)ws_size; (void)out_size;
  const float* x    = (const float*)d_in[0];
  const float* We1  = (const float*)d_in[1];
  const float* be1  = (const float*)d_in[2];
  const float* We2  = (const float*)d_in[3];
  const float* be2  = (const float*)d_in[4];
  const float* Wmu  = (const float*)d_in[5];
  const float* bmu  = (const float*)d_in[6];
  const float* Wlt  = (const float*)d_in[7];
  const float* blt  = (const float*)d_in[8];
  const float* Wd1  = (const float*)d_in[9];
  const float* bd1  = (const float*)d_in[10];
  const float* Wdmu = (const float*)d_in[11];
  const float* bdmu = (const float*)d_in[12];
  const float* Wds  = (const float*)d_in[13];
  const float* bds  = (const float*)d_in[14];
  const float* bmz  = (const float*)d_in[15];
  const float* blz  = (const float*)d_in[16];
  const float* noise= (const float*)d_in[17];
  float* out = (float*)d_out;

  vaebm_kernel<<<512, 256, 0, stream>>>(x, We1, be1, We2, be2, Wmu, bmu, Wlt, blt,
                                        Wd1, bd1, Wdmu, bdmu, Wds, bds,
                                        bmz, blz, noise, out);
}